// Round 2
// baseline (362.330 us; speedup 1.0000x reference)
//
#include <hip/hip_runtime.h>
#include <stdint.h>

// SmallMLP: x[65536,784] @ tern(w1[320,784])^T + b1 -> tern -> @ tern(w2[10,320])^T + b2 -> log_softmax
// R5: barrier-free register pipeline. R4 post-mortem: time pinned at 140us because every
// chunk ends in s_barrier whose implicit vmcnt(0) drains ALL loads block-wide (8 waves in
// lockstep at the slowest load's pace). Fix: drop LDS + __syncthreads from the main loop.
//   - B fragments load global->reg directly: for fixed nt a wave reads 1024 contiguous bytes
//     of q1t (L2-resident, 500 KB) — perfectly coalesced, no LDS needed.
//   - Double-buffered registers for A-raw and B-frags; waits are compiler-counted vmcnt on
//     register deps; loads have a full compute phase (~800-1600 cyc) in flight.
//   - Waves free-run (TLP latency hiding); barriers only in the (once) epilogue.

#define TERN_TH 0.001f

using bf16x8 = __attribute__((ext_vector_type(8))) short;   // 8 bf16 = 4 VGPR
using f32x4  = __attribute__((ext_vector_type(4))) float;   // 4 fp32 acc

__device__ __forceinline__ unsigned short f2bf(float f) {
    unsigned u = __float_as_uint(f);
    u = (u + 0x7FFFu + ((u >> 16) & 1u)) >> 16;   // RNE
    return (unsigned short)u;
}
__device__ __forceinline__ float ternf(float w) {
    return (w > TERN_TH) ? 1.0f : ((w < -TERN_TH) ? -1.0f : 0.0f);
}
// packed bf16 convert: [15:0]=bf16(a), [31:16]=bf16(b)
__device__ __forceinline__ unsigned cvt_pk_bf16(float a, float b) {
    unsigned r;
    asm("v_cvt_pk_bf16_f32 %0, %1, %2" : "=v"(r) : "v"(a), "v"(b));
    return r;
}

// ---------------- prep: ternarize w1 -> bf16, tiled [25 chunks][320 rows][32 k]
#define Q1T_ELEMS (25 * 320 * 32)
__global__ void prep_q1(const float* __restrict__ w1, unsigned short* __restrict__ q1t) {
    int idx = blockIdx.x * 256 + threadIdx.x;
    if (idx >= Q1T_ELEMS) return;
    int c  = idx / (320 * 32);
    int r  = idx % (320 * 32);
    int j  = r / 32;
    int kk = r % 32;
    int k  = c * 32 + kk;
    float v = (k < 784) ? ternf(w1[j * 784 + k]) : 0.0f;
    q1t[idx] = f2bf(v);
}

// ---------------- LDS layout (bytes) — epilogue only
#define LDS_H  0                     // [64][328] bf16 = 41984
#define LDS_Q2 41984                 // [16][328] bf16 = 10496
#define LDS_TOTAL 52480

__global__ __launch_bounds__(512, 2) void mlp_main(
    const float* __restrict__ x, const unsigned short* __restrict__ q1t,
    const float* __restrict__ b1, const float* __restrict__ w2,
    const float* __restrict__ b2, float* __restrict__ out) {

    __shared__ __attribute__((aligned(16))) unsigned char smem[LDS_TOTAL];
    unsigned short* sm16 = (unsigned short*)smem;

    const int tid  = threadIdx.x;
    const int lane = tid & 63;
    const int wave = tid >> 6;     // 8 waves
    const int quad = lane >> 4;
    const int l15  = lane & 15;
    const int wm   = wave >> 1;    // 0..3: 32-row group
    const int wn   = wave & 1;     // 0..1: 160-col half
    const int blk  = blockIdx.x;   // 512 blocks * 128 rows

    f32x4 acc[2][10];
#pragma unroll
    for (int mt = 0; mt < 2; ++mt)
#pragma unroll
        for (int nt = 0; nt < 10; ++nt) {
            f32x4 z = {0.f, 0.f, 0.f, 0.f};
            acc[mt][nt] = z;
        }

    // A fragment source: lane holds row (wm*32 + mt*16 + l15), k = quad*8..+8
    const float* xrow = x + (size_t)(blk * 128 + wm * 32 + l15) * 784;
    // B fragment source: chunk c, tile nt: byte (c*20480 + wn*10240 + nt*1024 + l15*64 + quad*16)
    const uint4* bptr = (const uint4*)((const unsigned char*)q1t + wn * 10240 + l15 * 64 + quad * 16);
    // chunk stride in uint4: 20480/16 = 1280; nt stride: 1024/16 = 64

    uint4  bA[10], bB[10];         // B frag double buffer (80 VGPR)
    float4 raA[2][2], raB[2][2];   // raw x double buffer (32 VGPR)
    bf16x8 ahi[2], alo[2];         // current chunk's A frags (16 VGPR)

    auto loadB = [&](int cc, uint4 (&dst)[10]) {
        if (cc >= 25) return;
        const uint4* p = bptr + (size_t)cc * 1280;
#pragma unroll
        for (int nt = 0; nt < 10; ++nt) dst[nt] = p[nt * 64];
    };
    auto loadA = [&](int cc, float4 (&ra)[2][2]) {
        if (cc >= 25) return;
        bool tail = (cc == 24) && (quad >= 2);   // k 784..799 pad
#pragma unroll
        for (int mt = 0; mt < 2; ++mt) {
            if (tail) {
                float4 z; z.x = z.y = z.z = z.w = 0.f;
                ra[mt][0] = z; ra[mt][1] = z;
            } else {
                const float4* p = (const float4*)(xrow + (size_t)mt * (16 * 784) + cc * 32 + quad * 8);
                ra[mt][0] = p[0]; ra[mt][1] = p[1];
            }
        }
    };
    // hi/lo bf16 split in registers (hw packed cvt; residual exact in fp32)
    auto convA = [&](float4 (&ra)[2][2]) {
#pragma unroll
        for (int mt = 0; mt < 2; ++mt) {
            float v[8] = {ra[mt][0].x, ra[mt][0].y, ra[mt][0].z, ra[mt][0].w,
                          ra[mt][1].x, ra[mt][1].y, ra[mt][1].z, ra[mt][1].w};
            union { unsigned w[4]; bf16x8 b; } uh, ul;
#pragma unroll
            for (int i = 0; i < 4; ++i) {
                unsigned hp = cvt_pk_bf16(v[2 * i], v[2 * i + 1]);
                float h0 = __uint_as_float(hp << 16);
                float h1 = __uint_as_float(hp & 0xffff0000u);
                uh.w[i] = hp;
                ul.w[i] = cvt_pk_bf16(v[2 * i] - h0, v[2 * i + 1] - h1);
            }
            ahi[mt] = uh.b; alo[mt] = ul.b;
        }
    };
    auto compute = [&](uint4 (&bq)[10]) {
#pragma unroll
        for (int nt = 0; nt < 10; ++nt) {
            union { uint4 u; bf16x8 b; } cb;
            cb.u = bq[nt];
#pragma unroll
            for (int mt = 0; mt < 2; ++mt) {
                acc[mt][nt] = __builtin_amdgcn_mfma_f32_16x16x32_bf16(ahi[mt], cb.b, acc[mt][nt], 0, 0, 0);
                acc[mt][nt] = __builtin_amdgcn_mfma_f32_16x16x32_bf16(alo[mt], cb.b, acc[mt][nt], 0, 0, 0);
            }
        }
    };

    // ---- prologue: chunks 0,1 in flight
    loadB(0, bA); loadA(0, raA);
    loadB(1, bB); loadA(1, raB);

    // ---- main loop: 12 pairs (chunks 0..23), chunk 24 in tail. No barriers.
#pragma unroll 1
    for (int cp = 0; cp < 12; ++cp) {
        const int c0 = 2 * cp;
        convA(raA);                 // frags for c0 (counted-vmcnt wait on raA)
        loadA(c0 + 2, raA);         // refill; ~2 compute phases of slack (covers HBM)
        compute(bA);                // 40 MFMA (waits bA via counted vmcnt)
        loadB(c0 + 2, bA);          // refill; ~1 compute phase of slack (L2-resident)
        convA(raB);
        loadA(c0 + 3, raB);
        compute(bB);
        loadB(c0 + 3, bB);
    }
    // chunk 24
    convA(raA);
    compute(bA);

    // ---------------- fused epilogue (layer 2 + log_softmax)
    __syncthreads();
    // stage q2: tern(w2) -> bf16 [16][328], rows 10..15 and cols 320..327 zero
    for (int idx = tid; idx < 16 * 328; idx += 512) {
        int o = idx / 328, j = idx % 328;
        float v = (o < 10 && j < 320) ? ternf(w2[o * 320 + j]) : 0.0f;
        sm16[(LDS_Q2 >> 1) + idx] = f2bf(v);
    }
    float b1v[10];
#pragma unroll
    for (int nt = 0; nt < 10; ++nt) b1v[nt] = b1[wn * 160 + nt * 16 + l15];
    float b2v = (l15 < 10) ? b2[l15] : 0.0f;

    for (int pass = 0; pass < 2; ++pass) {
        __syncthreads();
        // waves owning this 64-row half write ternarized h (bf16) to LDS
        if ((wm >> 1) == pass) {
#pragma unroll
            for (int mt = 0; mt < 2; ++mt)
#pragma unroll
                for (int nt = 0; nt < 10; ++nt)
#pragma unroll
                    for (int i = 0; i < 4; ++i) {
                        float hv = acc[mt][nt][i] + b1v[nt];
                        int row = (wm & 1) * 32 + mt * 16 + quad * 4 + i;   // C layout: col=l15, row=quad*4+reg
                        int col = wn * 160 + nt * 16 + l15;
                        sm16[(LDS_H >> 1) + row * 328 + col] = f2bf(ternf(hv));
                    }
        }
        __syncthreads();
        // layer 2: waves 0..3 compute 16 rows x 16 cols (10 valid), K=320
        if (wave < 4) {
            f32x4 acc2 = {0.f, 0.f, 0.f, 0.f};
#pragma unroll
            for (int kc = 0; kc < 10; ++kc) {
                bf16x8 a = *(const bf16x8*)(smem + LDS_H + (wave * 16 + l15) * 656 + kc * 64 + quad * 16);
                bf16x8 b = *(const bf16x8*)(smem + LDS_Q2 + l15 * 656 + kc * 64 + quad * 16);
                acc2 = __builtin_amdgcn_mfma_f32_16x16x32_bf16(a, b, acc2, 0, 0, 0);
            }
            // log_softmax across the 16 lanes holding one row (cols), 10 valid
#pragma unroll
            for (int i = 0; i < 4; ++i) {
                float l  = acc2[i] + b2v;
                float lm = (l15 < 10) ? l : -3.4e38f;
#pragma unroll
                for (int s = 8; s >= 1; s >>= 1) lm = fmaxf(lm, __shfl_xor(lm, s, 64));
                float e  = (l15 < 10) ? expf(l - lm) : 0.0f;
                float ss = e;
#pragma unroll
                for (int s = 8; s >= 1; s >>= 1) ss += __shfl_xor(ss, s, 64);
                float ov = (l - lm) - logf(ss);
                if (l15 < 10) {
                    int grow = blk * 128 + pass * 64 + wave * 16 + quad * 4 + i;
                    out[(size_t)grow * 10 + l15] = ov;
                }
            }
        }
    }
}

extern "C" void kernel_launch(void* const* d_in, const int* in_sizes, int n_in,
                              void* d_out, int out_size, void* d_ws, size_t ws_size,
                              hipStream_t stream) {
    const float* x  = (const float*)d_in[0];
    const float* w1 = (const float*)d_in[1];
    const float* b1 = (const float*)d_in[2];
    const float* w2 = (const float*)d_in[3];
    const float* b2 = (const float*)d_in[4];
    unsigned short* q1t = (unsigned short*)d_ws;   // 512000 B

    prep_q1<<<(Q1T_ELEMS + 255) / 256, 256, 0, stream>>>(w1, q1t);
    mlp_main<<<512, 512, 0, stream>>>(x, q1t, b1, w2, b2, (float*)d_out);
}

// Round 3
// 360.521 us; speedup vs baseline: 1.0050x; 1.0050x over previous
//
#include <hip/hip_runtime.h>
#include <stdint.h>

// SmallMLP: x[65536,784] @ tern(w1[320,784])^T + b1 -> tern -> @ tern(w2[10,320])^T + b2 -> log_softmax
// R6: occupancy/TLP fix. R3/R4 both pinned at 140us with ~7 waves/CU (unified VGPR+AGPR
// footprint ~288/wave capped residency; block waves lockstep via barriers). R5's free-form
// register pipeline was collapsed by the scheduler (VGPR 116) and regressed.
//   - 32 rows/block, 256 threads, 2048 blocks. Wave tile 16x160 -> acc[10] = 40 regs.
//   - B: single-buffer gll->LDS, m97 2-barrier chunk structure (barrier pins load issue
//     points; every load gets a full chunk-phase in flight; robust vs scheduler sinking).
//   - A: direct global->reg fragments, named 2-deep double buffer (no dynamic indexing).
//   - ~4 independent blocks/CU -> each SIMD hosts 4 waves from DIFFERENT blocks; one
//     block's barrier drain overlaps other blocks' compute (m114).

#define TERN_TH 0.001f

using bf16x8 = __attribute__((ext_vector_type(8))) short;   // 8 bf16 = 4 VGPR
using f32x4  = __attribute__((ext_vector_type(4))) float;   // 4 fp32 acc

typedef unsigned int u32;
#define AS1 __attribute__((address_space(1)))
#define AS3 __attribute__((address_space(3)))

__device__ __forceinline__ unsigned short f2bf(float f) {
    unsigned u = __float_as_uint(f);
    u = (u + 0x7FFFu + ((u >> 16) & 1u)) >> 16;   // RNE
    return (unsigned short)u;
}
__device__ __forceinline__ float ternf(float w) {
    return (w > TERN_TH) ? 1.0f : ((w < -TERN_TH) ? -1.0f : 0.0f);
}
// packed bf16 convert: [15:0]=bf16(a), [31:16]=bf16(b)
__device__ __forceinline__ unsigned cvt_pk_bf16(float a, float b) {
    unsigned r;
    asm("v_cvt_pk_bf16_f32 %0, %1, %2" : "=v"(r) : "v"(a), "v"(b));
    return r;
}

// ---------------- prep: ternarize w1 -> bf16, tiled [25 chunks][320 rows][32 k]
#define Q1T_ELEMS (25 * 320 * 32)
__global__ void prep_q1(const float* __restrict__ w1, unsigned short* __restrict__ q1t) {
    int idx = blockIdx.x * 256 + threadIdx.x;
    if (idx >= Q1T_ELEMS) return;
    int c  = idx / (320 * 32);
    int r  = idx % (320 * 32);
    int j  = r / 32;
    int kk = r % 32;
    int k  = c * 32 + kk;
    float v = (k < 784) ? ternf(w1[j * 784 + k]) : 0.0f;
    q1t[idx] = f2bf(v);
}

// ---------------- LDS layout (bytes)
#define LDS_B  0                     // main loop: [320 cols][32 k] bf16 = 20480
#define LDS_H  0                     // epilogue (overlaps B): [32][328] bf16 = 20992
#define LDS_Q2 20992                 // [16][328] bf16 = 10496 -> 31488
#define LDS_TOTAL 31488

#define BCHUNK_BYTES 20480           // 320*32*2

__global__ __launch_bounds__(256, 4) void mlp_main(
    const float* __restrict__ x, const unsigned short* __restrict__ q1t,
    const float* __restrict__ b1, const float* __restrict__ w2,
    const float* __restrict__ b2, float* __restrict__ out) {

    __shared__ __attribute__((aligned(16))) unsigned char smem[LDS_TOTAL];
    unsigned short* sm16 = (unsigned short*)smem;

    const int tid  = threadIdx.x;
    const int lane = tid & 63;
    const int wave = tid >> 6;     // 4 waves
    const int quad = lane >> 4;
    const int l15  = lane & 15;
    const int wm   = wave >> 1;    // 0..1: 16-row group
    const int wn   = wave & 1;     // 0..1: 160-col half
    const int blk  = blockIdx.x;   // 2048 blocks * 32 rows

    f32x4 acc[10];
#pragma unroll
    for (int nt = 0; nt < 10; ++nt) {
        f32x4 z = {0.f, 0.f, 0.f, 0.f};
        acc[nt] = z;
    }

    // A fragment source: lane holds row (wm*16 + l15), k = quad*8..+8
    const float* xrow = x + (size_t)(blk * 32 + wm * 16 + l15) * 784;

    float4 ra0[2], ra1[2];         // raw x, named double buffer (16 VGPR)
    bf16x8 ahi, alo;               // current chunk's A frags (8 VGPR)

    // B chunk stage: 20 KB = 5 calls x (4 waves x 64 lanes x 16 B); lds dest wave-uniform
    auto stageB = [&](int c) {
        const unsigned char* src = (const unsigned char*)q1t + (size_t)c * BCHUNK_BYTES;
#pragma unroll
        for (int i = 0; i < 5; ++i) {
            __builtin_amdgcn_global_load_lds(
                (const AS1 u32*)(src + i * 4096 + wave * 1024 + lane * 16),
                (AS3 u32*)(smem + LDS_B + i * 4096 + wave * 1024),
                16, 0, 0);
        }
    };
    auto loadA = [&](int cc, float4 (&ra)[2]) {
        bool tail = (cc == 24) && (quad >= 2);   // k 784..799 pad
        if (tail) {
            float4 z; z.x = z.y = z.z = z.w = 0.f;
            ra[0] = z; ra[1] = z;
        } else {
            const float4* p = (const float4*)(xrow + cc * 32 + quad * 8);
            ra[0] = p[0]; ra[1] = p[1];
        }
    };
    // hi/lo bf16 split in registers (hw packed cvt; residual exact in fp32)
    auto convA = [&](const float4 (&ra)[2]) {
        float v[8] = {ra[0].x, ra[0].y, ra[0].z, ra[0].w,
                      ra[1].x, ra[1].y, ra[1].z, ra[1].w};
        union { unsigned w[4]; bf16x8 b; } uh, ul;
#pragma unroll
        for (int i = 0; i < 4; ++i) {
            unsigned hp = cvt_pk_bf16(v[2 * i], v[2 * i + 1]);
            float h0 = __uint_as_float(hp << 16);
            float h1 = __uint_as_float(hp & 0xffff0000u);
            uh.w[i] = hp;
            ul.w[i] = cvt_pk_bf16(v[2 * i] - h0, v[2 * i + 1] - h1);
        }
        ahi = uh.b; alo = ul.b;
    };

    const int bqoff = wn * 10240 + l15 * 64 + quad * 16;   // B frag: col*64 + quad*16

    // one chunk: sync1 (B[c] landed) -> ds_read frags + convA -> sync2 (LDS free)
    //            -> issue gll B[c+1] + loadA(c+2) (fly across compute) -> 20 MFMA
    auto chunk = [&](int c, const float4 (&raCur)[2], float4 (&raNext)[2],
                     bool doStage, bool doLoadA) {
        __syncthreads();                       // B[c] in LDS (barrier drains vmcnt)
        uint4 bq[10];
#pragma unroll
        for (int nt = 0; nt < 10; ++nt)
            bq[nt] = *(const uint4*)(smem + LDS_B + bqoff + nt * 1024);
        convA(raCur);
        __syncthreads();                       // all waves done reading LDS_B
        if (doStage) stageB(c + 1);            // in flight across compute
        if (doLoadA) loadA(c + 2, raNext);     // in flight across compute + next chunk
#pragma unroll
        for (int nt = 0; nt < 10; ++nt) {
            union { uint4 u; bf16x8 b; } cb;
            cb.u = bq[nt];
            acc[nt] = __builtin_amdgcn_mfma_f32_16x16x32_bf16(ahi, cb.b, acc[nt], 0, 0, 0);
            acc[nt] = __builtin_amdgcn_mfma_f32_16x16x32_bf16(alo, cb.b, acc[nt], 0, 0, 0);
        }
    };

    // ---- prologue
    stageB(0);
    loadA(0, ra0);
    loadA(1, ra1);

    // ---- main loop: chunks 0..23 in pairs (static buffer names), chunk 24 tail
#pragma unroll 1
    for (int cp = 0; cp < 12; ++cp) {
        const int c0 = 2 * cp;
        chunk(c0,     ra0, ra0, true, true);          // loads chunk c0+2 into ra0
        chunk(c0 + 1, ra1, ra1, true, cp < 11);       // loads chunk c0+3 into ra1
    }
    chunk(24, ra0, ra0, false, false);

    // ---------------- fused epilogue (layer 2 + log_softmax)
    // All B-reads finished before last sync2; safe to overwrite LDS_B with H.
    float b1v[10];
#pragma unroll
    for (int nt = 0; nt < 10; ++nt) b1v[nt] = b1[wn * 160 + nt * 16 + l15];
    // write ternarized h (bf16) to LDS H[32][328]
#pragma unroll
    for (int nt = 0; nt < 10; ++nt)
#pragma unroll
        for (int i = 0; i < 4; ++i) {
            float hv = acc[nt][i] + b1v[nt];
            int row = wm * 16 + quad * 4 + i;          // C layout: col=l15, row=quad*4+reg
            int col = wn * 160 + nt * 16 + l15;
            sm16[(LDS_H >> 1) + row * 328 + col] = f2bf(ternf(hv));
        }
    // stage q2: tern(w2) -> bf16 [16][328], rows 10..15 and cols 320..327 zero
    for (int idx = tid; idx < 16 * 328; idx += 256) {
        int o = idx / 328, j = idx % 328;
        float v = (o < 10 && j < 320) ? ternf(w2[o * 320 + j]) : 0.0f;
        sm16[(LDS_Q2 >> 1) + idx] = f2bf(v);
    }
    __syncthreads();
    // layer 2: waves 0..1 compute 16 rows x 16 cols (10 valid), K=320
    if (wave < 2) {
        float b2v = (l15 < 10) ? b2[l15] : 0.0f;
        f32x4 acc2 = {0.f, 0.f, 0.f, 0.f};
#pragma unroll
        for (int kc = 0; kc < 10; ++kc) {
            bf16x8 a = *(const bf16x8*)(smem + LDS_H + (wave * 16 + l15) * 656 + kc * 64 + quad * 16);
            bf16x8 b = *(const bf16x8*)(smem + LDS_Q2 + l15 * 656 + kc * 64 + quad * 16);
            acc2 = __builtin_amdgcn_mfma_f32_16x16x32_bf16(a, b, acc2, 0, 0, 0);
        }
        // log_softmax across the 16 lanes holding one row (cols), 10 valid
#pragma unroll
        for (int i = 0; i < 4; ++i) {
            float l  = acc2[i] + b2v;
            float lm = (l15 < 10) ? l : -3.4e38f;
#pragma unroll
            for (int s = 8; s >= 1; s >>= 1) lm = fmaxf(lm, __shfl_xor(lm, s, 64));
            float e  = (l15 < 10) ? expf(l - lm) : 0.0f;
            float ss = e;
#pragma unroll
            for (int s = 8; s >= 1; s >>= 1) ss += __shfl_xor(ss, s, 64);
            float ov = (l - lm) - logf(ss);
            if (l15 < 10) {
                int grow = blk * 32 + wave * 16 + quad * 4 + i;
                out[(size_t)grow * 10 + l15] = ov;
            }
        }
    }
}

extern "C" void kernel_launch(void* const* d_in, const int* in_sizes, int n_in,
                              void* d_out, int out_size, void* d_ws, size_t ws_size,
                              hipStream_t stream) {
    const float* x  = (const float*)d_in[0];
    const float* w1 = (const float*)d_in[1];
    const float* b1 = (const float*)d_in[2];
    const float* w2 = (const float*)d_in[3];
    const float* b2 = (const float*)d_in[4];
    unsigned short* q1t = (unsigned short*)d_ws;   // 512000 B

    prep_q1<<<(Q1T_ELEMS + 255) / 256, 256, 0, stream>>>(w1, q1t);
    mlp_main<<<2048, 256, 0, stream>>>(x, q1t, b1, w2, b2, (float*)d_out);
}

// Round 4
// 324.943 us; speedup vs baseline: 1.1151x; 1.1095x over previous
//
#include <hip/hip_runtime.h>
#include <stdint.h>

// SmallMLP: x[65536,784] @ tern(w1[320,784])^T + b1 -> tern -> @ tern(w2[10,320])^T + b2 -> log_softmax
// R7: counted-vmcnt pipeline (T3/T4 port). R3/R4/R6 all pinned at ~140-155us because the
// compiler emits s_waitcnt vmcnt(0) before every __syncthreads -> every chunk serially pays
// full memory latency (13k stall cyc/chunk vs 1.5k work). R5 (no barriers) collapsed.
// Fix per m218 (+38-73%): raw s_barrier + hand-counted vmcnt(5), never 0, in the main loop.
//   - B: triple-buffered LDS via global_load_lds, issued 2 chunks ahead. B padded to 384
//     cols so all 8 waves issue exactly 3 gll calls/chunk -> uniform vmcnt counting.
//   - A: inline-asm global_load_dwordx4 into named reg slots, 2 chunks ahead, same FIFO.
//   - One s_waitcnt vmcnt(5) + one raw s_barrier per chunk; sched_barrier(0) fences (rule #18).
//   - 1024 blocks x 512 thr, 64 rows/block, wave tile 16x160 (acc[10]=40), LDS 72KB ->
//     2 blocks/CU = 4 waves/SIMD, VGPR target <=128.

#define TERN_TH 0.001f

using bf16x8 = __attribute__((ext_vector_type(8))) short;   // 8 bf16 = 4 VGPR
using f32x4  = __attribute__((ext_vector_type(4))) float;   // 4 fp32 acc
using f32x4v = __attribute__((ext_vector_type(4))) float;   // asm-friendly float4

typedef unsigned int u32;
#define AS1 __attribute__((address_space(1)))
#define AS3 __attribute__((address_space(3)))

__device__ __forceinline__ unsigned short f2bf(float f) {
    unsigned u = __float_as_uint(f);
    u = (u + 0x7FFFu + ((u >> 16) & 1u)) >> 16;   // RNE
    return (unsigned short)u;
}
__device__ __forceinline__ float ternf(float w) {
    return (w > TERN_TH) ? 1.0f : ((w < -TERN_TH) ? -1.0f : 0.0f);
}
__device__ __forceinline__ unsigned cvt_pk_bf16(float a, float b) {
    unsigned r;
    asm("v_cvt_pk_bf16_f32 %0, %1, %2" : "=v"(r) : "v"(a), "v"(b));
    return r;
}

// ---------------- prep: ternarize w1 -> bf16, tiled [25 chunks][384 cols][32 k] (cols 320.. pad 0)
#define Q1T_ELEMS (25 * 384 * 32)
__global__ void prep_q1(const float* __restrict__ w1, unsigned short* __restrict__ q1t) {
    int idx = blockIdx.x * 256 + threadIdx.x;
    if (idx >= Q1T_ELEMS) return;
    int c  = idx / (384 * 32);
    int r  = idx % (384 * 32);
    int j  = r / 32;
    int kk = r % 32;
    int k  = c * 32 + kk;
    float v = (j < 320 && k < 784) ? ternf(w1[j * 784 + k]) : 0.0f;
    q1t[idx] = f2bf(v);
}

// ---------------- LDS layout (bytes)
#define BUFB 24576                   // one B buffer: 384 cols * 32 k * 2 B
#define LDS_TOTAL (3 * BUFB)         // 73728; epilogue overlaps (H 41984 + Q2 10496 = 52480)
#define LDS_H  0
#define LDS_Q2 41984

__global__ __launch_bounds__(512, 4) void mlp_main(
    const float* __restrict__ x, const unsigned short* __restrict__ q1t,
    const float* __restrict__ b1, const float* __restrict__ w2,
    const float* __restrict__ b2, float* __restrict__ out) {

    __shared__ __attribute__((aligned(16))) unsigned char smem[LDS_TOTAL];
    unsigned short* sm16 = (unsigned short*)smem;

    const int tid  = threadIdx.x;
    const int lane = tid & 63;
    const int wave = tid >> 6;     // 8 waves
    const int quad = lane >> 4;
    const int l15  = lane & 15;
    const int wm   = wave >> 1;    // 0..3: 16-row group
    const int wn   = wave & 1;     // 0..1: 160-col half
    const int blk  = blockIdx.x;   // 1024 blocks * 64 rows

    f32x4 acc[10];
#pragma unroll
    for (int nt = 0; nt < 10; ++nt) {
        f32x4 z = {0.f, 0.f, 0.f, 0.f};
        acc[nt] = z;
    }

    // A fragment source: lane holds row (wm*16 + l15), k = quad*8..+8
    const float* xrow = x + (size_t)(blk * 64 + wm * 16 + l15) * 784;
    const int bqoff = wn * 10240 + l15 * 64 + quad * 16;   // B frag byte off within buffer

    f32x4v ra0_0, ra0_1, ra1_0, ra1_1;   // A raw, 2 named slots x 32 B
    bf16x8 ahi, alo;

    // ---- inline-asm A issue (2x dwordx4, NOT waited here; counted by the per-chunk vmcnt)
    auto issueA = [&](int cc, f32x4v& r0, f32x4v& r1) {
        // tail chunk 24: k 784..799 invalid for quad>=2 -> clamp addr (zeroed in final body)
        const float* p0 = (cc == 24 && quad >= 2) ? xrow : (xrow + cc * 32 + quad * 8);
        asm volatile("global_load_dwordx4 %0, %2, off\n\t"
                     "global_load_dwordx4 %1, %2, off offset:16"
                     : "=v"(r0), "=v"(r1) : "v"(p0) : "memory");
    };
    // ---- B stage for chunk c into buffer bi: 24 calls of 1024 B, 3 per wave (uniform)
    auto stage3 = [&](int c, int bi) {
        const unsigned char* src = (const unsigned char*)q1t + (size_t)c * BUFB;
        unsigned char* dst = smem + bi * BUFB;
#pragma unroll
        for (int i = 0; i < 3; ++i) {
            int call = wave + i * 8;
            __builtin_amdgcn_global_load_lds(
                (const AS1 u32*)(src + call * 1024 + lane * 16),
                (AS3 u32*)(dst + call * 1024),
                16, 0, 0);
        }
    };
    // ---- hi/lo bf16 split in registers
    auto convA = [&](const f32x4v& r0, const f32x4v& r1) {
        float v[8] = {r0.x, r0.y, r0.z, r0.w, r1.x, r1.y, r1.z, r1.w};
        union { unsigned w[4]; bf16x8 b; } uh, ul;
#pragma unroll
        for (int i = 0; i < 4; ++i) {
            unsigned hp = cvt_pk_bf16(v[2 * i], v[2 * i + 1]);
            float h0 = __uint_as_float(hp << 16);
            float h1 = __uint_as_float(hp & 0xffff0000u);
            uh.w[i] = hp;
            ul.w[i] = cvt_pk_bf16(v[2 * i] - h0, v[2 * i + 1] - h1);
        }
        ahi = uh.b; alo = ul.b;
    };

    int bc = 0;   // LDS buffer index of current chunk (c % 3)

    // one chunk body. FIFO per wave per body: [A(c+2) x2, gll(c+2) x3] -> steady-state
    // outstanding at top of body c: A(c+1)(2) + gll(c+1)(3) = 5 -> vmcnt(5) certifies
    // A(c) and gll(c) complete, with ~2 chunk-phases of slack. Raw s_barrier then makes
    // all waves' gll(c) writes visible, and certifies all waves finished reading the
    // buffer that gll(c+2) will overwrite (their ds_reads completed before their own
    // lgkm-waited MFMAs in body c-1, which precede this barrier).
    auto body = [&](int c, f32x4v& a0, f32x4v& a1, bool issue, bool fin) {
        if (fin) { asm volatile("s_waitcnt vmcnt(0)" ::: "memory"); }
        else     { asm volatile("s_waitcnt vmcnt(5)" ::: "memory"); }
        __builtin_amdgcn_sched_barrier(0);
        __builtin_amdgcn_s_barrier();
        __builtin_amdgcn_sched_barrier(0);
        const unsigned char* buf = smem + bc * BUFB;
        uint4 bq[10];
#pragma unroll
        for (int nt = 0; nt < 10; ++nt)
            bq[nt] = *(const uint4*)(buf + bqoff + nt * 1024);
        if (fin && quad >= 2) {          // zero the clamped tail lanes (k 784..799)
            f32x4v z = {0.f, 0.f, 0.f, 0.f};
            a0 = z; a1 = z;
        }
        convA(a0, a1);
        if (issue) {
            issueA(c + 2, a0, a1);       // reuse slot (c%2 == (c+2)%2); convA already read it
            stage3(c + 2, (bc + 2) % 3);
        }
        __builtin_amdgcn_sched_barrier(0);
#pragma unroll
        for (int nt = 0; nt < 10; ++nt) {
            union { uint4 u; bf16x8 b; } cb;
            cb.u = bq[nt];
            acc[nt] = __builtin_amdgcn_mfma_f32_16x16x32_bf16(ahi, cb.b, acc[nt], 0, 0, 0);
            acc[nt] = __builtin_amdgcn_mfma_f32_16x16x32_bf16(alo, cb.b, acc[nt], 0, 0, 0);
        }
        bc = (bc + 1) % 3;
    };

    // ---- prologue: chunks 0,1 in flight (FIFO: A0,gll0,A1,gll1 -> 10 outstanding)
    issueA(0, ra0_0, ra0_1);
    stage3(0, 0);
    issueA(1, ra1_0, ra1_1);
    stage3(1, 1);

    // ---- main loop: chunks 0..24, A slots alternate by parity
#pragma unroll 1
    for (int cp = 0; cp < 11; ++cp) {
        body(2 * cp,     ra0_0, ra0_1, true, false);
        body(2 * cp + 1, ra1_0, ra1_1, true, false);
    }
    body(22, ra0_0, ra0_1, true,  false);   // issues chunk 24
    body(23, ra1_0, ra1_1, false, false);
    body(24, ra0_0, ra0_1, false, true);

    // ---------------- fused epilogue (layer 2 + log_softmax)
    __syncthreads();   // full drain fine here (once)
    float b1v[10];
#pragma unroll
    for (int nt = 0; nt < 10; ++nt) b1v[nt] = b1[wn * 160 + nt * 16 + l15];
    // write ternarized h (bf16) to LDS H[64][328]
#pragma unroll
    for (int nt = 0; nt < 10; ++nt)
#pragma unroll
        for (int i = 0; i < 4; ++i) {
            float hv = acc[nt][i] + b1v[nt];
            int row = wm * 16 + quad * 4 + i;          // C layout: col=l15, row=quad*4+reg
            int col = wn * 160 + nt * 16 + l15;
            sm16[(LDS_H >> 1) + row * 328 + col] = f2bf(ternf(hv));
        }
    // stage q2: tern(w2) -> bf16 [16][328], rows 10..15 and cols 320..327 zero
    for (int idx = tid; idx < 16 * 328; idx += 512) {
        int o = idx / 328, j = idx % 328;
        float v = (o < 10 && j < 320) ? ternf(w2[o * 320 + j]) : 0.0f;
        sm16[(LDS_Q2 >> 1) + idx] = f2bf(v);
    }
    __syncthreads();
    // layer 2: waves 0..3 compute 16 rows x 16 cols (10 valid), K=320
    if (wave < 4) {
        float b2v = (l15 < 10) ? b2[l15] : 0.0f;
        f32x4 acc2 = {0.f, 0.f, 0.f, 0.f};
#pragma unroll
        for (int kc = 0; kc < 10; ++kc) {
            bf16x8 a = *(const bf16x8*)(smem + LDS_H + (wave * 16 + l15) * 656 + kc * 64 + quad * 16);
            bf16x8 b = *(const bf16x8*)(smem + LDS_Q2 + l15 * 656 + kc * 64 + quad * 16);
            acc2 = __builtin_amdgcn_mfma_f32_16x16x32_bf16(a, b, acc2, 0, 0, 0);
        }
        // log_softmax across the 16 lanes holding one row (cols), 10 valid
#pragma unroll
        for (int i = 0; i < 4; ++i) {
            float l  = acc2[i] + b2v;
            float lm = (l15 < 10) ? l : -3.4e38f;
#pragma unroll
            for (int s = 8; s >= 1; s >>= 1) lm = fmaxf(lm, __shfl_xor(lm, s, 64));
            float e  = (l15 < 10) ? expf(l - lm) : 0.0f;
            float ss = e;
#pragma unroll
            for (int s = 8; s >= 1; s >>= 1) ss += __shfl_xor(ss, s, 64);
            float ov = (l - lm) - logf(ss);
            if (l15 < 10) {
                int grow = blk * 64 + wave * 16 + quad * 4 + i;
                out[(size_t)grow * 10 + l15] = ov;
            }
        }
    }
}

extern "C" void kernel_launch(void* const* d_in, const int* in_sizes, int n_in,
                              void* d_out, int out_size, void* d_ws, size_t ws_size,
                              hipStream_t stream) {
    const float* x  = (const float*)d_in[0];
    const float* w1 = (const float*)d_in[1];
    const float* b1 = (const float*)d_in[2];
    const float* w2 = (const float*)d_in[3];
    const float* b2 = (const float*)d_in[4];
    unsigned short* q1t = (unsigned short*)d_ws;   // 614400 B

    prep_q1<<<(Q1T_ELEMS + 255) / 256, 256, 0, stream>>>(w1, q1t);
    mlp_main<<<1024, 512, 0, stream>>>(x, q1t, b1, w2, b2, (float*)d_out);
}